// Round 3
// baseline (917.423 us; speedup 1.0000x reference)
//
#include <hip/hip_runtime.h>
#include <math.h>

#define NB 8
#define LK 4096
#define LQ 4096
#define DD 512
#define LSEL 2744
#define LPAD 2784   // 58 * 48

typedef __attribute__((ext_vector_type(8))) short bf16x8;
typedef __attribute__((ext_vector_type(4))) float f32x4;

#define AS1 __attribute__((address_space(1)))
#define AS3 __attribute__((address_space(3)))

__device__ __forceinline__ unsigned short f2bf(float x) {
  unsigned u = __float_as_uint(x);
  unsigned r = (u + 0x7fffu + ((u >> 16) & 1u)) >> 16;
  return (unsigned short)r;
}

__device__ __forceinline__ unsigned fkey(float x) {
  unsigned b = __float_as_uint(x);
  return (b & 0x80000000u) ? ~b : (b | 0x80000000u);
}

// DPP reductions over 16-lane groups (VALU pipe, no LDS traffic)
__device__ __forceinline__ float rowmax16(float v) {
  int t;
  t = __builtin_amdgcn_update_dpp(0, __float_as_int(v), 0xB1, 0xF, 0xF, true);  // quad_perm xor1
  v = fmaxf(v, __int_as_float(t));
  t = __builtin_amdgcn_update_dpp(0, __float_as_int(v), 0x4E, 0xF, 0xF, true);  // quad_perm xor2
  v = fmaxf(v, __int_as_float(t));
  t = __builtin_amdgcn_update_dpp(0, __float_as_int(v), 0x124, 0xF, 0xF, true); // row_ror:4
  v = fmaxf(v, __int_as_float(t));
  t = __builtin_amdgcn_update_dpp(0, __float_as_int(v), 0x128, 0xF, 0xF, true); // row_ror:8
  v = fmaxf(v, __int_as_float(t));
  return v;
}
__device__ __forceinline__ float rowsum16(float v) {
  int t;
  t = __builtin_amdgcn_update_dpp(0, __float_as_int(v), 0xB1, 0xF, 0xF, true);
  v += __int_as_float(t);
  t = __builtin_amdgcn_update_dpp(0, __float_as_int(v), 0x4E, 0xF, 0xF, true);
  v += __int_as_float(t);
  t = __builtin_amdgcn_update_dpp(0, __float_as_int(v), 0x124, 0xF, 0xF, true);
  v += __int_as_float(t);
  t = __builtin_amdgcn_update_dpp(0, __float_as_int(v), 0x128, 0xF, 0xF, true);
  v += __int_as_float(t);
  return v;
}

// keys f32 [B][LK][D] -> keysT f32 [B][D][LK]  (+ fused bf16 cast of keys)
__global__ void k_transpose(const float* __restrict__ keys, float* __restrict__ keysT,
                            unsigned short* __restrict__ kbf) {
  __shared__ float tile[32][33];
  int b = blockIdx.z;
  int k0 = blockIdx.x * 32, d0 = blockIdx.y * 32;
  int tx = threadIdx.x, ty = threadIdx.y;
  const float* src = keys + ((size_t)b * LK + k0) * DD + d0;
#pragma unroll
  for (int i = 0; i < 4; i++) {
    float v = src[(size_t)(ty + 8 * i) * DD + tx];
    tile[ty + 8 * i][tx] = v;
    kbf[((size_t)b * LK + k0 + ty + 8 * i) * DD + d0 + tx] = f2bf(v);
  }
  __syncthreads();
  float* dst = keysT + ((size_t)b * DD + d0) * LK + k0;
#pragma unroll
  for (int i = 0; i < 4; i++) dst[(size_t)(ty + 8 * i) * LK + tx] = tile[tx][ty + 8 * i];
}

// values f32 [B][LK][D] -> chunk-tiled bf16 VT [B][LK/8][D][8keys]  (+ fused mean partials)
__global__ void k_vt(const float* __restrict__ values, unsigned short* __restrict__ vt,
                     float* __restrict__ part) {
  __shared__ float tile[32][65];
  __shared__ float psum[4][64];
  int b = blockIdx.z, k0 = blockIdx.x * 32, d0 = blockIdx.y * 64;
  int tid = threadIdx.x;
  const float* src = values + ((size_t)b * LK + k0) * DD + d0;
#pragma unroll
  for (int j = 0; j < 8; j++) {
    int li = tid + 256 * j;
    tile[li >> 6][li & 63] = src[(size_t)(li >> 6) * DD + (li & 63)];
  }
  __syncthreads();
  int c = tid >> 6, d = tid & 63;
  union { unsigned short us[8]; uint4 v; } pk;
  float fs = 0.f;
#pragma unroll
  for (int j = 0; j < 8; j++) {
    float v = tile[c * 8 + j][d];
    pk.us[j] = f2bf(v);
    fs += v;
  }
  size_t ci = ((size_t)b * (LK / 8) + (size_t)(k0 >> 3) + c) * DD + d0 + d;
  ((uint4*)vt)[ci] = pk.v;
  psum[c][d] = fs;
  __syncthreads();
  if (tid < 64) {
    float s = psum[0][tid] + psum[1][tid] + psum[2][tid] + psum[3][tid];
    part[((size_t)b * 128 + (k0 >> 5)) * DD + d0 + tid] = s;
  }
}

// per-(b,d): mean of top-LSEL of keysT row, exact radix select
__global__ __launch_bounds__(256) void k_kreduce(const float* __restrict__ keysT, float* __restrict__ kred) {
  __shared__ float vals[4096];
  __shared__ unsigned hist[16];
  __shared__ double redd[256];
  __shared__ unsigned redu[256];
  int row = blockIdx.x;
  int tid = threadIdx.x;
  const float* src = keysT + (size_t)row * LK;
  for (int i = tid; i < LK; i += 256) vals[i] = src[i];
  __syncthreads();
  unsigned prefix = 0;
  int rank = LSEL;
  for (int shift = 28; shift >= 0; shift -= 4) {
    if (tid < 16) hist[tid] = 0;
    __syncthreads();
    unsigned cnt[16];
#pragma unroll
    for (int j = 0; j < 16; j++) cnt[j] = 0;
    for (int i = tid; i < LK; i += 256) {
      unsigned u = fkey(vals[i]);
      bool cand = (shift == 28) || ((u >> (shift + 4)) == prefix);
      if (cand) cnt[(u >> shift) & 15]++;
    }
#pragma unroll
    for (int j = 0; j < 16; j++) if (cnt[j]) atomicAdd(&hist[j], cnt[j]);
    __syncthreads();
    int r = rank;
    unsigned bin = 15;
    for (;;) {
      int c = (int)hist[bin];
      if (c >= r) break;
      r -= c;
      if (bin == 0) break;
      bin--;
    }
    prefix = (prefix << 4) | bin;
    rank = r;
    __syncthreads();
  }
  double fsum = 0.0;
  unsigned fcnt = 0;
  for (int i = tid; i < LK; i += 256) {
    unsigned u = fkey(vals[i]);
    if (u > prefix) { fsum += (double)vals[i]; fcnt++; }
  }
  redd[tid] = fsum; redu[tid] = fcnt;
  __syncthreads();
  for (int s = 128; s > 0; s >>= 1) {
    if (tid < s) { redd[tid] += redd[tid + s]; redu[tid] += redu[tid + s]; }
    __syncthreads();
  }
  if (tid == 0) {
    unsigned u = prefix;
    unsigned bits = (u & 0x80000000u) ? (u ^ 0x80000000u) : ~u;
    float tval = __uint_as_float(bits);
    kred[row] = (float)((redd[0] + (double)(LSEL - (int)redu[0]) * (double)tval) / (double)LSEL);
  }
}

// sqk[b][q] = dot(K_reduce[b], queries[b][q]) with f64 accumulation
__global__ __launch_bounds__(256) void k_sqk(const float* __restrict__ queries, const float* __restrict__ kred,
                                             float* __restrict__ sqk) {
  int gw = blockIdx.x * 4 + (threadIdx.x >> 6);
  int lane = threadIdx.x & 63;
  int b = gw >> 12;
  const float* qp = queries + (size_t)gw * DD;
  const float* kp = kred + (size_t)b * DD;
  float4 a0 = ((const float4*)qp)[lane * 2];
  float4 a1 = ((const float4*)qp)[lane * 2 + 1];
  float4 c0 = ((const float4*)kp)[lane * 2];
  float4 c1 = ((const float4*)kp)[lane * 2 + 1];
  double s = (double)a0.x * c0.x + (double)a0.y * c0.y + (double)a0.z * c0.z + (double)a0.w * c0.w +
             (double)a1.x * c1.x + (double)a1.y * c1.y + (double)a1.z * c1.z + (double)a1.w * c1.w;
#pragma unroll
  for (int m = 1; m < 64; m <<= 1) s += __shfl_xor(s, m);
  if (lane == 0) sqk[gw] = (float)s;
}

// per-batch: exact top-LSEL selection (ties by lowest index) + per-row selection flags
__global__ __launch_bounds__(512) void k_select(const float* __restrict__ sqk, int* __restrict__ qidx,
                                                unsigned char* __restrict__ selflag) {
  __shared__ float vals[4096];
  __shared__ unsigned hist[16];
  __shared__ unsigned wsum[8];
  int b = blockIdx.x, tid = threadIdx.x;
  const float* src = sqk + (size_t)b * LQ;
  for (int i = tid; i < LQ; i += 512) vals[i] = src[i];
  __syncthreads();
  unsigned prefix = 0;
  int rank = LSEL;
  for (int shift = 28; shift >= 0; shift -= 4) {
    if (tid < 16) hist[tid] = 0;
    __syncthreads();
    unsigned cnt[16];
#pragma unroll
    for (int j = 0; j < 16; j++) cnt[j] = 0;
    for (int i = tid; i < LQ; i += 512) {
      unsigned u = fkey(vals[i]);
      bool cand = (shift == 28) || ((u >> (shift + 4)) == prefix);
      if (cand) cnt[(u >> shift) & 15]++;
    }
#pragma unroll
    for (int j = 0; j < 16; j++) if (cnt[j]) atomicAdd(&hist[j], cnt[j]);
    __syncthreads();
    int r = rank;
    unsigned bin = 15;
    for (;;) {
      int c = (int)hist[bin];
      if (c >= r) break;
      r -= c;
      if (bin == 0) break;
      bin--;
    }
    prefix = (prefix << 4) | bin;
    rank = r;
    __syncthreads();
  }
  unsigned gt = 0, eq = 0;
#pragma unroll
  for (int j = 0; j < 8; j++) {
    int i = tid * 8 + j;
    unsigned u = fkey(vals[i]);
    gt += (u > prefix) ? 1u : 0u;
    eq += (u == prefix) ? 1u : 0u;
  }
  unsigned packed = (gt << 16) | eq;
  unsigned x = packed;
  int lane = tid & 63, wv = tid >> 6;
#pragma unroll
  for (int off2 = 1; off2 < 64; off2 <<= 1) {
    unsigned t = __shfl_up(x, off2);
    if (lane >= off2) x += t;
  }
  if (lane == 63) wsum[wv] = x;
  __syncthreads();
  unsigned wpre = 0, total = 0;
#pragma unroll
  for (int i = 0; i < 8; i++) {
    unsigned v = wsum[i];
    if (i < wv) wpre += v;
    total += v;
  }
  unsigned exclv = x + wpre - packed;
  unsigned total_gt = total >> 16;
  unsigned need_eq = (unsigned)LSEL - total_gt;
  unsigned gpos = exclv >> 16;
  unsigned epos = exclv & 0xffffu;
  for (int j = 0; j < 8; j++) {
    int i = tid * 8 + j;
    unsigned u = fkey(vals[i]);
    unsigned char fl = 0;
    if (u > prefix) {
      qidx[(size_t)b * LPAD + gpos] = i;
      gpos++;
      fl = 1;
    } else if (u == prefix) {
      if (epos < need_eq) {
        qidx[(size_t)b * LPAD + total_gt + epos] = i;
        fl = 1;
      }
      epos++;
    }
    selflag[(size_t)b * LQ + i] = fl;
  }
  for (int p = LSEL + tid; p < LPAD; p += 512) qidx[(size_t)b * LPAD + p] = -1;
}

// gather selected queries -> bf16 [B][LPAD][D] (pad rows zero)
__global__ void k_gather(const float* __restrict__ queries, const int* __restrict__ qidx,
                         unsigned short* __restrict__ qs) {
  int r = blockIdx.x, b = blockIdx.y;
  int tid = threadIdx.x;
  int q = qidx[(size_t)b * LPAD + r];
  ushort4* dst = (ushort4*)(qs + ((size_t)b * LPAD + r) * DD);
  if (q < 0) {
    ushort4 z; z.x = 0; z.y = 0; z.z = 0; z.w = 0;
    dst[tid] = z;
  } else {
    const float4* srcv = (const float4*)(queries + ((size_t)b * LQ + q) * DD);
    float4 v = srcv[tid];
    ushort4 o;
    o.x = f2bf(v.x); o.y = f2bf(v.y); o.z = f2bf(v.z); o.w = f2bf(v.w);
    dst[tid] = o;
  }
}

__global__ void k_meanv_fin(const float* __restrict__ part, float* __restrict__ meanv) {
  int d = blockIdx.x * 256 + threadIdx.x;
  int b = blockIdx.y;
  float s = 0.f;
  for (int i = 0; i < 128; i++) s += part[((size_t)b * 128 + i) * DD + d];
  meanv[(size_t)b * DD + d] = s * (1.0f / 4096.0f);
}

// fill ONLY unselected rows with mean-of-values (selected rows written by k_attn)
__global__ void k_fill(float4* __restrict__ out4, const float4* __restrict__ mv4,
                       const unsigned char* __restrict__ flag) {
  int row = blockIdx.x * 2 + (threadIdx.x >> 7);
  int t = threadIdx.x & 127;
  if (flag[row]) return;
  int b = row >> 12;
  out4[(size_t)row * 128 + t] = mv4[b * 128 + t];
}

// flash attention v3: 3 waves x 16q (Q-tile 48), KVBLK 32, single-buffered K+V (67KB ->
// 2 blocks/CU for cross-block phase overlap), DPP softmax, defer-max.
__global__ __launch_bounds__(192, 2) void k_attn(const unsigned short* __restrict__ qs,
                                                 const unsigned short* __restrict__ kbf,
                                                 const unsigned short* __restrict__ vt,
                                                 const int* __restrict__ qidx,
                                                 float* __restrict__ out) {
  extern __shared__ char smem[];
  // layout: K [32768] @0, V [32768] @32768, P [3][1024] @65536
  int b = blockIdx.y;
  int q0 = blockIdx.x * 48;
  int tid = threadIdx.x;
  int w = tid >> 6, lane = tid & 63;
  int l15 = lane & 15, l4 = lane >> 4;
  unsigned short* Pl = (unsigned short*)(smem + 65536 + w * 1024);

  const unsigned short* qrow = qs + ((size_t)b * LPAD + q0 + w * 16 + l15) * DD;
  bf16x8 qf[16];
#pragma unroll
  for (int t = 0; t < 16; t++) qf[t] = *(const bf16x8*)(qrow + t * 32 + l4 * 8);

  f32x4 O[32];
#pragma unroll
  for (int i = 0; i < 32; i++) O[i] = (f32x4){0.f, 0.f, 0.f, 0.f};
  float m_run[4], l_run[4];
#pragma unroll
  for (int r = 0; r < 4; r++) { m_run[r] = -1e30f; l_run[r] = 0.f; }

  const float SCALE = 0.04419417418f;  // 1/sqrt(512)

  const char* gKbase = (const char*)(kbf + (size_t)b * LK * DD);
  const char* gVbase = (const char*)vt;
  const unsigned short* Kl = (const unsigned short*)smem;
  const unsigned short* Vl = (const unsigned short*)(smem + 32768);

  for (int kt = 0; kt < LK / 32; kt++) {
    // stage K+V for this tile (async global->LDS, 1KB per load)
    for (int u = w; u < 64; u += 3) {
      if (u < 32) {
        const char* srcp = gKbase + (size_t)(kt * 32 + u) * 1024 + ((lane ^ (u & 7)) << 4);
        __builtin_amdgcn_global_load_lds((const AS1 unsigned int*)(uintptr_t)srcp,
                                         (AS3 unsigned int*)(uintptr_t)(smem + u * 1024), 16, 0, 0);
      } else {
        int li = u - 32;
        int c = li >> 3;
        size_t vidx = (((size_t)b * 512 + (size_t)(kt * 4 + c)) * 512 + (li & 7) * 64 + lane);
        const char* srcp = gVbase + vidx * 16;
        __builtin_amdgcn_global_load_lds((const AS1 unsigned int*)(uintptr_t)srcp,
                                         (AS3 unsigned int*)(uintptr_t)(smem + 32768 + li * 1024),
                                         16, 0, 0);
      }
    }
    __syncthreads();  // vmcnt drained by each wave; all staged data visible

    // QK^T: S[16q x 32k] per wave, full-D contraction
    f32x4 accS0 = (f32x4){0.f, 0.f, 0.f, 0.f};
    f32x4 accS1 = (f32x4){0.f, 0.f, 0.f, 0.f};
#pragma unroll
    for (int t = 0; t < 16; t++) {
      int cc = t * 4 + l4;
      bf16x8 bk0 = *(const bf16x8*)(Kl + (size_t)l15 * 512 + ((cc ^ (l15 & 7)) * 8));
      accS0 = __builtin_amdgcn_mfma_f32_16x16x32_bf16(qf[t], bk0, accS0, 0, 0, 0);
      int k1r = 16 + l15;
      bf16x8 bk1 = *(const bf16x8*)(Kl + (size_t)k1r * 512 + ((cc ^ (k1r & 7)) * 8));
      accS1 = __builtin_amdgcn_mfma_f32_16x16x32_bf16(qf[t], bk1, accS1, 0, 0, 0);
    }

    // online softmax with defer-max (THR=8), DPP 16-lane reductions
    float s0v[4], s1v[4], mx_[4];
    float need = 0.f;
#pragma unroll
    for (int r = 0; r < 4; r++) {
      float s0 = accS0[r] * SCALE, s1 = accS1[r] * SCALE;
      float mx = rowmax16(fmaxf(s0, s1));
      mx_[r] = mx;
      need = fmaxf(need, mx - m_run[r]);
      s0v[r] = s0; s1v[r] = s1;
    }
    if (!__all(need <= 8.0f)) {
#pragma unroll
      for (int r = 0; r < 4; r++) {
        float mn = fmaxf(m_run[r], mx_[r]);
        float f = __expf(m_run[r] - mn);
        m_run[r] = mn;
        l_run[r] *= f;
#pragma unroll
        for (int nt = 0; nt < 32; nt++) O[nt][r] *= f;
      }
    }
#pragma unroll
    for (int r = 0; r < 4; r++) {
      float p0 = __expf(s0v[r] - m_run[r]);
      float p1 = __expf(s1v[r] - m_run[r]);
      l_run[r] += rowsum16(p0 + p1);
      int row = l4 * 4 + r;
      int sw = (row >> 1) & 3;
      Pl[row * 32 + (((l15 >> 3) ^ sw) * 8) + (l15 & 7)] = f2bf(p0);
      int key1 = 16 + l15;
      Pl[row * 32 + (((key1 >> 3) ^ sw) * 8) + (key1 & 7)] = f2bf(p1);
    }

    // PV: O[16q x 512d] += P[16x32] * V[32x512]  (same-wave P, no barrier needed)
    bf16x8 aP = *(const bf16x8*)(Pl + l15 * 32 + ((l4 ^ ((l15 >> 1) & 3)) * 8));
#pragma unroll
    for (int nt = 0; nt < 32; nt++) {
      bf16x8 bv = *(const bf16x8*)(Vl + ((size_t)l4 * 512 + nt * 16 + l15) * 8);
      O[nt] = __builtin_amdgcn_mfma_f32_16x16x32_bf16(aP, bv, O[nt], 0, 0, 0);
    }

    __syncthreads();  // all reads of K/V done before next stage overwrites
  }

  // epilogue: divide by l and scatter to output rows
#pragma unroll
  for (int r = 0; r < 4; r++) {
    int qp = q0 + w * 16 + l4 * 4 + r;
    int qg = qidx[(size_t)b * LPAD + qp];
    if (qg >= 0) {
      float inv = 1.0f / l_run[r];
      float* orow = out + ((size_t)b * LQ + qg) * DD;
#pragma unroll
      for (int nt = 0; nt < 32; nt++) orow[nt * 16 + l15] = O[nt][r] * inv;
    }
  }
}

extern "C" void kernel_launch(void* const* d_in, const int* in_sizes, int n_in,
                              void* d_out, int out_size, void* d_ws, size_t ws_size,
                              hipStream_t stream) {
  const float* queries = (const float*)d_in[0];
  const float* keys = (const float*)d_in[1];
  const float* values = (const float*)d_in[2];
  float* out = (float*)d_out;
  char* ws = (char*)d_ws;
  size_t off = 0;
  float* keysT = (float*)(ws + off); off += (size_t)NB * DD * LK * 4;                 // 64 MB
  unsigned short* kbf = (unsigned short*)(ws + off); off += (size_t)NB * LK * DD * 2; // 32 MB
  unsigned short* vt = (unsigned short*)(ws + off); off += (size_t)NB * LK * DD * 2;  // 32 MB
  float* kred = (float*)(ws + off); off += (size_t)NB * DD * 4;
  float* sqkv = (float*)(ws + off); off += (size_t)NB * LQ * 4;
  int* qidx = (int*)(ws + off); off += (size_t)NB * LPAD * 4;
  float* part = (float*)(ws + off); off += (size_t)NB * 128 * DD * 4;                 // 2 MB
  float* meanv = (float*)(ws + off); off += (size_t)NB * DD * 4;
  unsigned char* selflag = (unsigned char*)(ws + off); off += (size_t)NB * LQ;
  // qs aliases keysT's region: keysT is dead after k_kreduce, qs written by k_gather after it
  unsigned short* qs = (unsigned short*)keysT;  // 22.8 MB < 64 MB

  hipFuncSetAttribute((const void*)k_attn, hipFuncAttributeMaxDynamicSharedMemorySize, 68608);

  k_transpose<<<dim3(LK / 32, DD / 32, NB), dim3(32, 8), 0, stream>>>(keys, keysT, kbf);
  k_vt<<<dim3(LK / 32, DD / 64, NB), 256, 0, stream>>>(values, vt, part);
  k_kreduce<<<NB * DD, 256, 0, stream>>>(keysT, kred);
  k_sqk<<<NB * LQ / 4, 256, 0, stream>>>(queries, kred, sqkv);
  k_select<<<NB, 512, 0, stream>>>(sqkv, qidx, selflag);
  k_gather<<<dim3(LPAD, NB), 128, 0, stream>>>(queries, qidx, qs);
  k_meanv_fin<<<dim3(DD / 256, NB), 256, 0, stream>>>(part, meanv);
  k_fill<<<NB * LQ / 2, 256, 0, stream>>>((float4*)out, (const float4*)meanv, selflag);
  k_attn<<<dim3(LPAD / 48, NB), 192, 68608, stream>>>(qs, kbf, vt, qidx, out);
}